// Round 1
// baseline (251.994 us; speedup 1.0000x reference)
//
#include <hip/hip_runtime.h>
#include <math.h>

#define BB 2
#define HH 256
#define WW 832
#define BHW (BB * HH * WW)

// ---------------------------------------------------------------------------
// Pass 1: 3x3 box sum with WRAP-AROUND boundaries (jnp.roll semantics),
// for both src and dst maps.
// ---------------------------------------------------------------------------
__global__ void blur_kernel(const float* __restrict__ src, const float* __restrict__ dst,
                            float* __restrict__ bS, float* __restrict__ bD) {
    int idx = blockIdx.x * blockDim.x + threadIdx.x;
    if (idx >= BHW) return;
    int j = idx % WW;
    int t = idx / WW;
    int i = t % HH;
    int base = (t / HH) * HH * WW;
    const float* s = src + base;
    const float* d = dst + base;
    float accS = 0.f, accD = 0.f;
#pragma unroll
    for (int di = -1; di <= 1; ++di) {
        int ii = i + di;
        ii = (ii < 0) ? ii + HH : ((ii >= HH) ? ii - HH : ii);
#pragma unroll
        for (int dj = -1; dj <= 1; ++dj) {
            int jj = j + dj;
            jj = (jj < 0) ? jj + WW : ((jj >= WW) ? jj - WW : jj);
            accS += s[ii * WW + jj];
            accD += d[ii * WW + jj];
        }
    }
    bS[idx] = accS;
    bD[idx] = accD;
}

// ---------------------------------------------------------------------------
// Pass 2: jnp.gradient (central diff interior, one-sided at edges) + atan2
// ---------------------------------------------------------------------------
__global__ void theta_kernel(const float* __restrict__ bS, const float* __restrict__ bD,
                             float* __restrict__ thS, float* __restrict__ thD) {
    int idx = blockIdx.x * blockDim.x + threadIdx.x;
    if (idx >= BHW) return;
    int j = idx % WW;
    int t = idx / WW;
    int i = t % HH;
    int base = idx - i * WW - j;  // b*H*W

    const float* maps[2];
    maps[0] = bS; maps[1] = bD;
    float* outs[2];
    outs[0] = thS; outs[1] = thD;

#pragma unroll
    for (int m = 0; m < 2; ++m) {
        const float* bm = maps[m] + base;
        float gyg, gxg;
        if (i == 0)            gyg = bm[WW + j] - bm[j];
        else if (i == HH - 1)  gyg = bm[(HH - 1) * WW + j] - bm[(HH - 2) * WW + j];
        else                   gyg = 0.5f * (bm[(i + 1) * WW + j] - bm[(i - 1) * WW + j]);
        int r = i * WW;
        if (j == 0)            gxg = bm[r + 1] - bm[r];
        else if (j == WW - 1)  gxg = bm[r + WW - 1] - bm[r + WW - 2];
        else                   gxg = 0.5f * (bm[r + j + 1] - bm[r + j - 1]);
        outs[m][idx] = atan2f(gyg, gxg);
    }
}

// ---------------------------------------------------------------------------
// Pass 3: sparsify (5x5 min-linear-index among edges) + 105-offset
// correspondence search with distance+orientation scoring.
// Tie-break: first k in provided xx/yy order (strict <) == jnp.argmin.
// ---------------------------------------------------------------------------
__global__ void disp_kernel(const float* __restrict__ src, const float* __restrict__ dst,
                            const float* __restrict__ thS, const float* __restrict__ thD,
                            const int* __restrict__ xx, const int* __restrict__ yy, int K,
                            float* __restrict__ dispx, float* __restrict__ dispy,
                            float* __restrict__ act) {
    int idx = blockIdx.x * blockDim.x + threadIdx.x;
    if (idx >= BHW) return;
    int j = idx % WW;
    int t = idx / WW;
    int i = t % HH;
    int base = (t / HH) * HH * WW;
    const float* s = src + base;

    float dxv = 0.f, dyv = 0.f, av = 0.f;
    if (s[i * WW + j] > 0.5f) {
        // keep = my linear index is the min among edge pixels in the 5x5 window
        bool keep = true;
        int mylin = i * WW + j;
        for (int di = -2; di <= 2 && keep; ++di) {
            int ii = i + di;
            if (ii < 0 || ii >= HH) continue;
            for (int dj = -2; dj <= 2; ++dj) {
                int jj = j + dj;
                if (jj < 0 || jj >= WW) continue;
                int nl = ii * WW + jj;
                if (nl < mylin && s[nl] > 0.5f) { keep = false; break; }
            }
        }
        if (keep) {
            const float* d = dst + base;
            const float* td = thD + base;
            float ts = thS[idx];
            float best = 1e9f;
            int bi = -1;
            for (int k = 0; k < K; ++k) {
                int ox = xx[k], oy = yy[k];
                int ii = i + oy, jj = j + ox;
                if (ii < 0 || ii >= HH || jj < 0 || jj >= WW) continue;
                if (d[ii * WW + jj] > 0.5f) {
                    float ang = 1.0f - cosf(ts - td[ii * WW + jj]);
                    float dist = sqrtf((float)(ox * ox + oy * oy));
                    float sc = 20.0f * dist + 10.5f * ang;  // PIX_W*dist + MULLINE_W*ALPHA_W*ang
                    if (sc < best) { best = sc; bi = k; }
                }
            }
            if (bi >= 0) {
                dxv = (float)xx[bi];
                dyv = (float)yy[bi];
                av = 1.0f;
            }
        }
    }
    dispx[idx] = dxv;
    dispy[idx] = dyv;
    act[idx] = av;
}

// ---------------------------------------------------------------------------
// Pass 4: 21x21 weighted diffusion of sparse displacements + final coords.
// dispx/dispy are exactly 0 where inactive, so mask-skip is exact.
// ---------------------------------------------------------------------------
__global__ void diffuse_kernel(const float* __restrict__ dispx, const float* __restrict__ dispy,
                               const float* __restrict__ act, float* __restrict__ out) {
    __shared__ float wt[441];
    int tid = threadIdx.y * 32 + threadIdx.x;
    for (int t = tid; t < 441; t += 256) {
        int dy = t / 21 - 10;
        int dx = t % 21 - 10;
        wt[t] = expf(-sqrtf((float)(dx * dx + dy * dy)) / 5.0f);
    }
    __syncthreads();

    int j = blockIdx.x * 32 + threadIdx.x;   // W = 26*32
    int i = blockIdx.y * 8 + threadIdx.y;    // H = 32*8
    int b = blockIdx.z;
    int base = b * HH * WW;
    const float* ax = dispx + base;
    const float* ay = dispy + base;
    const float* am = act + base;

    float nx = 0.f, ny = 0.f, den = 0.f;
    for (int dy = -10; dy <= 10; ++dy) {
        int ii = i + dy;
        if (ii < 0 || ii >= HH) continue;
        int row = ii * WW;
        const float* wrow = &wt[(dy + 10) * 21 + 10];
        for (int dx = -10; dx <= 10; ++dx) {
            int jj = j + dx;
            if (jj < 0 || jj >= WW) continue;
            float m = am[row + jj];
            if (m != 0.f) {
                float w = wrow[dx];
                den += w;
                nx += w * ax[row + jj];
                ny += w * ay[row + jj];
            }
        }
    }
    float inv = 0.6f / (den + 1e-6f);
    out[base * 2 + i * WW + j] = (float)j + nx * inv;
    out[base * 2 + HH * WW + i * WW + j] = (float)i + ny * inv;
}

// ---------------------------------------------------------------------------
extern "C" void kernel_launch(void* const* d_in, const int* in_sizes, int n_in,
                              void* d_out, int out_size, void* d_ws, size_t ws_size,
                              hipStream_t stream) {
    const float* src = (const float*)d_in[0];
    const float* dst = (const float*)d_in[1];
    const int* xx = (const int*)d_in[2];
    const int* yy = (const int*)d_in[3];
    int K = in_sizes[2];  // 105

    float* ws = (float*)d_ws;
    // region layout (each BHW floats): 0=bS(->dispx) 1=bD(->dispy) 2=thS 3=thD 4=act
    float* bS  = ws;
    float* bD  = ws + (size_t)BHW;
    float* thS = ws + 2 * (size_t)BHW;
    float* thD = ws + 3 * (size_t)BHW;
    float* act = ws + 4 * (size_t)BHW;
    float* out = (float*)d_out;

    dim3 blk(256);
    dim3 grd((BHW + 255) / 256);
    blur_kernel<<<grd, blk, 0, stream>>>(src, dst, bS, bD);
    theta_kernel<<<grd, blk, 0, stream>>>(bS, bD, thS, thD);
    // bS/bD are dead after theta_kernel; reuse them as dispx/dispy
    disp_kernel<<<grd, blk, 0, stream>>>(src, dst, thS, thD, xx, yy, K, bS, bD, act);
    diffuse_kernel<<<dim3(WW / 32, HH / 8, BB), dim3(32, 8), 0, stream>>>(bS, bD, act, out);
}

// Round 2
// 143.828 us; speedup vs baseline: 1.7520x; 1.7520x over previous
//
#include <hip/hip_runtime.h>
#include <math.h>

#define BB 2
#define HH 256
#define WW 832
#define HWIMG (HH * WW)
#define BHW (BB * HWIMG)

#define TXN 26            // tiles in x (832/32)
#define TYN 8             // tiles in y (256/32)
#define NTILES (BB * TXN * TYN)   // 416
#define CAP 512           // per-tile candidate capacity (avg ~40 expected)

// ---------------------------------------------------------------------------
// Pass 1: 3x3 box sum with WRAP-AROUND boundaries (jnp.roll semantics).
// ---------------------------------------------------------------------------
__global__ void blur_kernel(const float* __restrict__ src, const float* __restrict__ dst,
                            float* __restrict__ bS, float* __restrict__ bD) {
    int idx = blockIdx.x * blockDim.x + threadIdx.x;
    if (idx >= BHW) return;
    int j = idx % WW;
    int t = idx / WW;
    int i = t % HH;
    int base = (t / HH) * HWIMG;
    const float* s = src + base;
    const float* d = dst + base;
    float accS = 0.f, accD = 0.f;
#pragma unroll
    for (int di = -1; di <= 1; ++di) {
        int ii = i + di;
        ii = (ii < 0) ? ii + HH : ((ii >= HH) ? ii - HH : ii);
#pragma unroll
        for (int dj = -1; dj <= 1; ++dj) {
            int jj = j + dj;
            jj = (jj < 0) ? jj + WW : ((jj >= WW) ? jj - WW : jj);
            accS += s[ii * WW + jj];
            accD += d[ii * WW + jj];
        }
    }
    bS[idx] = accS;
    bD[idx] = accD;
}

// ---------------------------------------------------------------------------
// Pass 2: jnp.gradient (central interior, one-sided edges) + atan2
// ---------------------------------------------------------------------------
__global__ void theta_kernel(const float* __restrict__ bS, const float* __restrict__ bD,
                             float* __restrict__ thS, float* __restrict__ thD) {
    int idx = blockIdx.x * blockDim.x + threadIdx.x;
    if (idx >= BHW) return;
    int j = idx % WW;
    int t = idx / WW;
    int i = t % HH;
    int base = idx - i * WW - j;

    const float* maps[2] = {bS, bD};
    float* outs[2] = {thS, thD};
#pragma unroll
    for (int m = 0; m < 2; ++m) {
        const float* bm = maps[m] + base;
        float gyg, gxg;
        if (i == 0)            gyg = bm[WW + j] - bm[j];
        else if (i == HH - 1)  gyg = bm[(HH - 1) * WW + j] - bm[(HH - 2) * WW + j];
        else                   gyg = 0.5f * (bm[(i + 1) * WW + j] - bm[(i - 1) * WW + j]);
        int r = i * WW;
        if (j == 0)            gxg = bm[r + 1] - bm[r];
        else if (j == WW - 1)  gxg = bm[r + WW - 1] - bm[r + WW - 2];
        else                   gxg = 0.5f * (bm[r + j + 1] - bm[r + j - 1]);
        outs[m][idx] = atan2f(gyg, gxg);
    }
}

// ---------------------------------------------------------------------------
// Pass 3 (fused): sparsify + correspondence search + bin active points into
// per-tile candidate lists. Packed entry: j(10b) | i(8b) | dx+7(4b) | dy+3(3b)
// ---------------------------------------------------------------------------
__global__ void search_kernel(const float* __restrict__ src, const float* __restrict__ dst,
                              const float* __restrict__ thS, const float* __restrict__ thD,
                              const int* __restrict__ xx, const int* __restrict__ yy, int K,
                              int* __restrict__ counts, int* __restrict__ entries) {
    __shared__ int kox[128], koy[128];
    __shared__ float kd[128];
    for (int t = threadIdx.x; t < K; t += blockDim.x) {
        int ox = xx[t], oy = yy[t];
        kox[t] = ox; koy[t] = oy;
        kd[t] = 20.0f * sqrtf((float)(ox * ox + oy * oy));
    }
    __syncthreads();

    int idx = blockIdx.x * blockDim.x + threadIdx.x;
    if (idx >= BHW) return;
    int j = idx % WW;
    int t = idx / WW;
    int i = t % HH;
    int b = t / HH;
    const float* s = src + b * HWIMG;
    if (s[i * WW + j] <= 0.5f) return;

    // keep iff no edge pixel with smaller linear index in the 5x5 window
    int mylin = i * WW + j;
    for (int di = -2; di <= 2; ++di) {
        int ii = i + di;
        if (ii < 0 || ii >= HH) continue;
        for (int dj = -2; dj <= 2; ++dj) {
            int jj = j + dj;
            if (jj < 0 || jj >= WW) continue;
            int nl = ii * WW + jj;
            if (nl < mylin && s[nl] > 0.5f) return;
        }
    }

    const float* d = dst + b * HWIMG;
    const float* td = thD + b * HWIMG;
    float ts = thS[idx];
    float best = 1e9f;
    int bi = -1;
    for (int k = 0; k < K; ++k) {
        int ii = i + koy[k], jj = j + kox[k];
        if (ii < 0 || ii >= HH || jj < 0 || jj >= WW) continue;
        if (d[ii * WW + jj] > 0.5f) {
            float sc = kd[k] + 10.5f * (1.0f - cosf(ts - td[ii * WW + jj]));
            if (sc < best) { best = sc; bi = k; }  // strict <: first-k tie-break (jnp.argmin)
        }
    }
    if (bi < 0) return;

    int dx = kox[bi], dy = koy[bi];
    int packed = j | (i << 10) | ((dx + 7) << 18) | ((dy + 3) << 22);
    int tx0 = max(j - 10, 0) >> 5, tx1 = min(j + 10, WW - 1) >> 5;
    int ty0 = max(i - 10, 0) >> 5, ty1 = min(i + 10, HH - 1) >> 5;
    for (int ty = ty0; ty <= ty1; ++ty)
        for (int tx = tx0; tx <= tx1; ++tx) {
            int tile = (b * TYN + ty) * TXN + tx;
            int pos = atomicAdd(&counts[tile], 1);
            if (pos < CAP) entries[tile * CAP + pos] = packed;
        }
}

// ---------------------------------------------------------------------------
// Pass 4: per-tile sparse diffusion. One block per 32x32 tile; candidates in
// LDS; each thread accumulates 4 pixels over the candidate list.
// ---------------------------------------------------------------------------
__global__ void diffuse_kernel(const int* __restrict__ counts, const int* __restrict__ entries,
                               float* __restrict__ out) {
    __shared__ float wt[441];
    __shared__ float4 ent[CAP];
    int tid = threadIdx.y * 32 + threadIdx.x;
    for (int t = tid; t < 441; t += 256) {
        int dy = t / 21 - 10;
        int dx = t % 21 - 10;
        wt[t] = expf(-sqrtf((float)(dx * dx + dy * dy)) / 5.0f);
    }
    int tx = blockIdx.x, ty = blockIdx.y, b = blockIdx.z;
    int tile = (b * TYN + ty) * TXN + tx;
    int cnt = counts[tile];
    if (cnt > CAP) cnt = CAP;
    const int* e = entries + tile * CAP;
    for (int t = tid; t < cnt; t += 256) {
        int p = e[t];
        ent[t] = make_float4((float)(p & 1023), (float)((p >> 10) & 255),
                             (float)(((p >> 18) & 15) - 7), (float)(((p >> 22) & 7) - 3));
    }
    __syncthreads();

    int j = tx * 32 + threadIdx.x;
    int i0 = ty * 32 + threadIdx.y * 4;   // rows i0..i0+3
    float nx0 = 0, ny0 = 0, de0 = 0;
    float nx1 = 0, ny1 = 0, de1 = 0;
    float nx2 = 0, ny2 = 0, de2 = 0;
    float nx3 = 0, ny3 = 0, de3 = 0;

    for (int c = 0; c < cnt; ++c) {
        float4 E = ent[c];                 // broadcast LDS read
        int dj = (int)E.x - j;
        if (dj < -10 || dj > 10) continue;
        int di = (int)E.y - i0;            // row r has offset di - r
        const float* wrow = &wt[dj + 10];
        if (di >= -10 && di <= 10)         { float w = wrow[(di + 10) * 21]; de0 += w; nx0 += w * E.z; ny0 += w * E.w; }
        if (di >= -9  && di <= 11)         { float w = wrow[(di + 9)  * 21]; de1 += w; nx1 += w * E.z; ny1 += w * E.w; }
        if (di >= -8  && di <= 12)         { float w = wrow[(di + 8)  * 21]; de2 += w; nx2 += w * E.z; ny2 += w * E.w; }
        if (di >= -7  && di <= 13)         { float w = wrow[(di + 7)  * 21]; de3 += w; nx3 += w * E.z; ny3 += w * E.w; }
    }

    int obase = b * 2 * HWIMG;
    float inv;
    inv = 0.6f / (de0 + 1e-6f);
    out[obase + (i0 + 0) * WW + j] = (float)j + nx0 * inv;
    out[obase + HWIMG + (i0 + 0) * WW + j] = (float)(i0 + 0) + ny0 * inv;
    inv = 0.6f / (de1 + 1e-6f);
    out[obase + (i0 + 1) * WW + j] = (float)j + nx1 * inv;
    out[obase + HWIMG + (i0 + 1) * WW + j] = (float)(i0 + 1) + ny1 * inv;
    inv = 0.6f / (de2 + 1e-6f);
    out[obase + (i0 + 2) * WW + j] = (float)j + nx2 * inv;
    out[obase + HWIMG + (i0 + 2) * WW + j] = (float)(i0 + 2) + ny2 * inv;
    inv = 0.6f / (de3 + 1e-6f);
    out[obase + (i0 + 3) * WW + j] = (float)j + nx3 * inv;
    out[obase + HWIMG + (i0 + 3) * WW + j] = (float)(i0 + 3) + ny3 * inv;
}

// ---------------------------------------------------------------------------
extern "C" void kernel_launch(void* const* d_in, const int* in_sizes, int n_in,
                              void* d_out, int out_size, void* d_ws, size_t ws_size,
                              hipStream_t stream) {
    const float* src = (const float*)d_in[0];
    const float* dst = (const float*)d_in[1];
    const int* xx = (const int*)d_in[2];
    const int* yy = (const int*)d_in[3];
    int K = in_sizes[2];  // 105

    float* ws = (float*)d_ws;
    float* bS  = ws;
    float* bD  = ws + (size_t)BHW;
    float* thS = ws + 2 * (size_t)BHW;
    float* thD = ws + 3 * (size_t)BHW;
    int*   counts  = (int*)(ws + 4 * (size_t)BHW);
    int*   entries = counts + NTILES;
    float* out = (float*)d_out;

    dim3 blk(256);
    dim3 grd((BHW + 255) / 256);
    blur_kernel<<<grd, blk, 0, stream>>>(src, dst, bS, bD);
    theta_kernel<<<grd, blk, 0, stream>>>(bS, bD, thS, thD);
    hipMemsetAsync(counts, 0, NTILES * sizeof(int), stream);
    search_kernel<<<grd, blk, 0, stream>>>(src, dst, thS, thD, xx, yy, K, counts, entries);
    diffuse_kernel<<<dim3(TXN, TYN, BB), dim3(32, 8), 0, stream>>>(counts, entries, out);
}